// Round 5
// baseline (193.249 us; speedup 1.0000x reference)
//
#include <hip/hip_runtime.h>
#include <math.h>

// Problem constants (from reference): B=8, Cin=32, Cout=32, S=256,
// REGION=64, OVERLAP=0 -> 4x4 regions, MAX_M=16.
#define NB 8
#define CIN 32
#define COUT 32
#define SS 256
#define REG 64
#define NMAX 16

// Workspace layout (bytes):
#define AVG_OFF   0
#define NM_OFF    1024
#define USED_OFF  2048
#define C64_OFF   4096
#define CN_OFF    4352
#define Y_OFF     8192
#define XE_OFF    (8u << 20)
#define XO_OFF    (12u << 20)
#define Z_OFF     (16u << 20)

// One block per (r, b): mean of 64x64 region of error signal, fp64 accum.
// Block (0,0) additionally computes the cas tables (one entry per thread).
__global__ void k_avg(const float* __restrict__ err, float* __restrict__ avg,
                      float* __restrict__ cyc64, float* __restrict__ cycN) {
    int r = blockIdx.x, b = blockIdx.y;
    int t = threadIdx.x;
    if (r == 0 && b == 0) {
        if (t < 64) {
            double a = (2.0 * M_PI / 64.0) * (double)t;
            cyc64[t] = (float)(cos(a) + sin(a));
        } else if (t < 64 + 136) {
            int e = t - 64;
            int n = 1;
            while (n * (n + 1) / 2 <= e) ++n;   // smallest n with n(n+1)/2 > e
            int j = e - n * (n - 1) / 2;
            double a = (2.0 * M_PI / (double)n) * (double)j;
            cycN[e] = (float)(cos(a) + sin(a));
        }
    }
    int ri = r >> 2, rj = r & 3;
    const float* base = err + ((size_t)b * SS + ri * REG) * SS + rj * REG;
    double s = 0.0;
    for (int it = 0; it < 16; ++it) {
        int u = it * 4 + (t >> 6);
        int v = t & 63;
        s += (double)base[(size_t)u * SS + v];
    }
    __shared__ double sm[256];
    sm[t] = s;
    __syncthreads();
    for (int w = 128; w > 0; w >>= 1) {
        if (t < w) sm[t] += sm[t + w];
        __syncthreads();
    }
    if (t == 0) avg[r * 8 + b] = (float)(sm[0] / 4096.0);
}

// Single block: per-region batch min/max normalize -> nm, plus used-n flags.
__global__ void k_nm(const float* __restrict__ avg, int* __restrict__ nm,
                     int* __restrict__ used) {
    int t = threadIdx.x;
    if (t < 32) used[t] = 0;
    __syncthreads();
    if (t < 16) {
        int r = t;
        float mn = avg[r * 8], mx = mn;
        for (int b = 1; b < NB; ++b) {
            float v = avg[r * 8 + b];
            mn = fminf(mn, v);
            mx = fmaxf(mx, v);
        }
        float d = mx - mn;
        bool ok = ((double)d > 1e-8);
        for (int b = 0; b < NB; ++b) {
            float norm = ok ? (avg[r * 8 + b] - mn) / d : 0.0f;
            float tt = norm * 15.0f;
            int nv = (int)tt + 1;
            if (nv > NMAX) nv = NMAX;
            nm[b * 16 + r] = nv;
            atomicOr(&used[nv], 1);
        }
    }
}

// One block per (i, r, b): n-corner separable DHT of the 64x64 region, then
// true n x n dht2 via row-column + correction, then Xe/Xo split. 256 threads.
// Stage 1 runs on a single wave with 4 p-rows per lane: one R4 read per u
// (4-way broadcast, ~free) instead of 4 waves each streaming the full R.
__global__ void k_fwd(const float* __restrict__ x, const int* __restrict__ nm,
                      const float* __restrict__ cyc64, const float* __restrict__ cycN,
                      float* __restrict__ Xe, float* __restrict__ Xo) {
    int i = blockIdx.x, r = blockIdx.y, b = blockIdx.z;
    int n = nm[b * 16 + r];
    int nn = n * n;
    int ri = r >> 2, rj = r & 3;
    int t = threadIdx.x;

    __shared__ __align__(16) float R[64 * 64];
    __shared__ __align__(16) float M1[16 * 68];   // stride 68: conflict-free rows
    __shared__ float H[256];
    __shared__ float T1[256];
    __shared__ float T2[256];
    __shared__ float cyc64L[64];
    __shared__ float cnL[16];

    if (t < 64) cyc64L[t] = cyc64[t];
    if (t < n)  cnL[t] = cycN[(n * (n - 1)) / 2 + t];

    const float* base = x + (((size_t)(b * CIN + i)) * SS + ri * REG) * SS + rj * REG;
    float4* R4 = (float4*)R;
    {
        int u0 = t >> 4, c4 = t & 15;
        for (int it = 0; it < 4; ++it) {
            int u = it * 16 + u0;
            R4[u * 16 + c4] = *(const float4*)(base + (size_t)u * SS + c4 * 4);
        }
    }
    __syncthreads();

    // stage 1 (wave 0 only): lane (qd=t>>4, vg=t&15) accumulates rows
    // p = qd + 4j over all u. n is block-uniform -> uniform j guards.
    if (t < 64) {
        int vg = t & 15, qd = t >> 4;
        int p0 = qd, p1 = qd + 4, p2 = qd + 8, p3 = qd + 12;
        float4 a0 = {0.f,0.f,0.f,0.f}, a1 = a0, a2 = a0, a3 = a0;
        int i0 = 0, i1 = 0, i2 = 0, i3 = 0;
        for (int u = 0; u < 64; ++u) {
            float4 rv = R4[u * 16 + vg];
            {
                float c = cyc64L[i0]; i0 = (i0 + p0) & 63;
                a0.x += c * rv.x; a0.y += c * rv.y; a0.z += c * rv.z; a0.w += c * rv.w;
            }
            if (n > 4) {
                float c = cyc64L[i1]; i1 = (i1 + p1) & 63;
                a1.x += c * rv.x; a1.y += c * rv.y; a1.z += c * rv.z; a1.w += c * rv.w;
            }
            if (n > 8) {
                float c = cyc64L[i2]; i2 = (i2 + p2) & 63;
                a2.x += c * rv.x; a2.y += c * rv.y; a2.z += c * rv.z; a2.w += c * rv.w;
            }
            if (n > 12) {
                float c = cyc64L[i3]; i3 = (i3 + p3) & 63;
                a3.x += c * rv.x; a3.y += c * rv.y; a3.z += c * rv.z; a3.w += c * rv.w;
            }
        }
        if (p0 < n) *(float4*)&M1[p0 * 68 + vg * 4] = a0;
        if (p1 < n) *(float4*)&M1[p1 * 68 + vg * 4] = a1;
        if (p2 < n) *(float4*)&M1[p2 * 68 + vg * 4] = a2;
        if (p3 < n) *(float4*)&M1[p3 * 68 + vg * 4] = a3;
    }
    __syncthreads();

    int p = 0, q = 0;
    if (t < nn) { p = t / n; q = t - p * n; }

    // stage 2: H[p][q] = sum_v M1[p][v] * cas64(q*v)
    if (t < nn) {
        float acc = 0.f;
        int idx = 0;
        for (int v = 0; v < 64; ++v) {
            acc += M1[p * 68 + v] * cyc64L[idx];
            idx = (idx + q) & 63;
        }
        H[t] = acc;
    }
    __syncthreads();

    // stage 3: true 2-D DHT of H (n x n) = row-column + correction (2n^3, not n^4)
    if (t < nn) {
        float acc = 0.f;
        int idx = 0;
        for (int v = 0; v < n; ++v) {
            acc += H[p * n + v] * cnL[idx];
            idx += q; if (idx >= n) idx -= n;
        }
        T1[p * n + q] = acc;   // T1[u][q]
    }
    __syncthreads();
    if (t < nn) {
        float acc = 0.f;
        int idx = 0;
        for (int u = 0; u < n; ++u) {
            acc += T1[u * n + q] * cnL[idx];
            idx += p; if (idx >= n) idx -= n;
        }
        T2[t] = acc;           // separable transform
    }
    __syncthreads();
    if (t < nn) {
        int pf = (p == 0) ? 0 : n - p;
        int qf = (q == 0) ? 0 : n - q;
        H[t] = 0.5f * (T2[p * n + q] + T2[pf * n + q] + T2[p * n + qf] - T2[pf * n + qf]);
    }
    __syncthreads();

    if (t < nn) {
        int fk = (t == 0) ? 0 : nn - t;
        float a = H[t], c = H[fk];
        size_t o = (((size_t)(b * 16 + r)) * CIN + i) * 256 + t;
        Xe[o] = 0.5f * (a + c);
        Xo[o] = 0.5f * (a - c);
    }
}

// dht2 of weights[:, :, :n, :n] for each used n, row-column + correction.
__global__ void k_wt(const float* __restrict__ wts, const int* __restrict__ used,
                     const float* __restrict__ cycN, float* __restrict__ Y) {
    int n = blockIdx.y + 1;
    if (!used[n]) return;
    int io = blockIdx.x;
    int t = threadIdx.x;
    int nn = n * n;
    __shared__ float Wt[256];
    __shared__ float T1[256];
    __shared__ float T2[256];
    __shared__ float cnL[16];
    Wt[t] = wts[(size_t)io * 256 + t];
    if (t < n) cnL[t] = cycN[(n * (n - 1)) / 2 + t];
    __syncthreads();
    int p = 0, q = 0;
    if (t < nn) { p = t / n; q = t - p * n; }
    if (t < nn) {
        float acc = 0.f;
        int idx = 0;
        for (int v = 0; v < n; ++v) {
            acc += Wt[p * 16 + v] * cnL[idx];
            idx += q; if (idx >= n) idx -= n;
        }
        T1[p * n + q] = acc;
    }
    __syncthreads();
    if (t < nn) {
        float acc = 0.f;
        int idx = 0;
        for (int u = 0; u < n; ++u) {
            acc += T1[u * n + q] * cnL[idx];
            idx += p; if (idx >= n) idx -= n;
        }
        T2[t] = acc;
    }
    __syncthreads();
    if (t < nn) {
        int pf = (p == 0) ? 0 : n - p;
        int qf = (q == 0) ? 0 : n - q;
        float v = 0.5f * (T2[p * n + q] + T2[pf * n + q] + T2[p * n + qf] - T2[pf * n + qf]);
        int m = n - 1;
        int ps2 = m * (m + 1) * (2 * m + 1) / 6;  // sum of squares 1..m
        Y[(size_t)1024 * ps2 + (size_t)io * nn + t] = v;
    }
}

// Z[o,k] = sum_i Xe[i,k]*Y[io,k] + Xo[i,k]*Y[io,flip(k)].
// grid (8, 128): blockIdx.x = group of 4 outputs, blockIdx.y = (b,r).
__global__ void k_z(const float* __restrict__ Xe, const float* __restrict__ Xo,
                    const float* __restrict__ Y, const int* __restrict__ nm,
                    float* __restrict__ Z) {
    int br = blockIdx.y;
    int og = blockIdx.x * 4;
    int b = br >> 4, r = br & 15;
    int n = nm[b * 16 + r];
    int nn = n * n;
    int t = threadIdx.x;
    if (t >= nn) return;
    int m = n - 1;
    int ps2 = m * (m + 1) * (2 * m + 1) / 6;
    const float* Yb = Y + (size_t)1024 * ps2;
    int fk = (t == 0) ? 0 : nn - t;
    float acc[4] = {0.f, 0.f, 0.f, 0.f};
    size_t xbase = (size_t)br * CIN * 256;
    for (int i = 0; i < CIN; ++i) {
        float xe = Xe[xbase + i * 256 + t];
        float xo = Xo[xbase + i * 256 + t];
        const float* yi = Yb + (size_t)(i * COUT + og) * nn;
#pragma unroll
        for (int oo = 0; oo < 4; ++oo) {
            acc[oo] += xe * yi[oo * nn + t] + xo * yi[oo * nn + fk];
        }
    }
    size_t zbase = (size_t)br * COUT * 256;
#pragma unroll
    for (int oo = 0; oo < 4; ++oo) Z[zbase + (og + oo) * 256 + t] = acc[oo];
}

// One block per (o, r, b): inverse dht2 via row-column + correction (/n^2),
// then n->64 separable expansion (/4096). The final stage register-caches
// each lane's E1 column slice (n float4, unrolled+guarded -> stays in VGPRs)
// and reuses it across the lane's 4 output rows.
__global__ void k_out(const float* __restrict__ Z, const int* __restrict__ nm,
                      const float* __restrict__ cyc64, const float* __restrict__ cycN,
                      float* __restrict__ out) {
    int o = blockIdx.x, r = blockIdx.y, b = blockIdx.z;
    int n = nm[b * 16 + r];
    int nn = n * n;
    int t = threadIdx.x;
    int br = b * 16 + r;

    __shared__ float Zs[256];
    __shared__ float T1[256];
    __shared__ float T2[256];
    __shared__ float Bk[256];
    __shared__ __align__(16) float E1[16 * 64];
    __shared__ float cyc64L[64];
    __shared__ float cnL[16];

    if (t < 64) cyc64L[t] = cyc64[t];
    if (t < n)  cnL[t] = cycN[(n * (n - 1)) / 2 + t];
    if (t < nn) Zs[t] = Z[((size_t)br * COUT + o) * 256 + t];
    __syncthreads();

    int p = 0, q = 0;
    if (t < nn) { p = t / n; q = t - p * n; }

    // inverse dht2 (row-column + correction), / nn
    if (t < nn) {
        float acc = 0.f;
        int idx = 0;
        for (int v = 0; v < n; ++v) {
            acc += Zs[p * n + v] * cnL[idx];
            idx += q; if (idx >= n) idx -= n;
        }
        T1[p * n + q] = acc;
    }
    __syncthreads();
    if (t < nn) {
        float acc = 0.f;
        int idx = 0;
        for (int u = 0; u < n; ++u) {
            acc += T1[u * n + q] * cnL[idx];
            idx += p; if (idx >= n) idx -= n;
        }
        T2[t] = acc;
    }
    __syncthreads();
    if (t < nn) {
        int pf = (p == 0) ? 0 : n - p;
        int qf = (q == 0) ? 0 : n - q;
        Bk[t] = 0.5f * (T2[p * n + q] + T2[pf * n + q] + T2[p * n + qf] - T2[pf * n + qf])
                / (float)nn;
    }
    __syncthreads();

    // E1[p][v] = sum_q Bk[p*n+q] * cas64(q*v)
    for (int mm = t; mm < n * 64; mm += 256) {
        int pp = mm >> 6, v = mm & 63;
        float acc = 0.f;
        int idx = 0;
        for (int qq = 0; qq < n; ++qq) {
            acc += Bk[pp * n + qq] * cyc64L[idx];
            idx = (idx + v) & 63;
        }
        E1[pp * 64 + v] = acc;
    }
    __syncthreads();

    // out[u][v] = (1/4096) sum_p E1[p][v] * cas64(p*u); E1 slice in registers.
    int ri = r >> 2, rj = r & 3;
    float* ob = out + (((size_t)(b * COUT + o)) * SS + ri * REG) * SS + rj * REG;
    const float4* E14 = (const float4*)E1;
    const float inv = 1.0f / 4096.0f;
    int u0 = t >> 4, vg = t & 15;
    float4 e[16];
#pragma unroll
    for (int pp = 0; pp < 16; ++pp) {
        if (pp < n) e[pp] = E14[pp * 16 + vg];
    }
    for (int it = 0; it < 4; ++it) {
        int u = it * 16 + u0;
        float4 acc = {0.f, 0.f, 0.f, 0.f};
#pragma unroll
        for (int pp = 0; pp < 16; ++pp) {
            if (pp < n) {
                float c = cyc64L[(pp * u) & 63];
                acc.x += c * e[pp].x; acc.y += c * e[pp].y;
                acc.z += c * e[pp].z; acc.w += c * e[pp].w;
            }
        }
        acc.x *= inv; acc.y *= inv; acc.z *= inv; acc.w *= inv;
        *(float4*)(ob + (size_t)u * SS + vg * 4) = acc;
    }
}

extern "C" void kernel_launch(void* const* d_in, const int* in_sizes, int n_in,
                              void* d_out, int out_size, void* d_ws, size_t ws_size,
                              hipStream_t stream) {
    const float* x   = (const float*)d_in[0];
    const float* err = (const float*)d_in[1];
    const float* wts = (const float*)d_in[2];
    float* out = (float*)d_out;
    char* ws = (char*)d_ws;

    float* avg   = (float*)(ws + AVG_OFF);
    int*   nm    = (int*)  (ws + NM_OFF);
    int*   used  = (int*)  (ws + USED_OFF);
    float* cyc64 = (float*)(ws + C64_OFF);
    float* cycN  = (float*)(ws + CN_OFF);
    float* Y     = (float*)(ws + Y_OFF);
    float* Xe    = (float*)(ws + XE_OFF);
    float* Xo    = (float*)(ws + XO_OFF);
    float* Z     = (float*)(ws + Z_OFF);

    k_avg<<<dim3(16, NB), 256, 0, stream>>>(err, avg, cyc64, cycN);
    k_nm<<<1, 32, 0, stream>>>(avg, nm, used);
    k_fwd<<<dim3(CIN, 16, NB), 256, 0, stream>>>(x, nm, cyc64, cycN, Xe, Xo);
    k_wt<<<dim3(CIN * COUT, NMAX), 256, 0, stream>>>(wts, used, cycN, Y);
    k_z<<<dim3(8, 128), 256, 0, stream>>>(Xe, Xo, Y, nm, Z);
    k_out<<<dim3(COUT, 16, NB), 256, 0, stream>>>(Z, nm, cyc64, cycN, out);
}

// Round 6
// 178.647 us; speedup vs baseline: 1.0817x; 1.0817x over previous
//
#include <hip/hip_runtime.h>
#include <math.h>

// Problem constants (from reference): B=8, Cin=32, Cout=32, S=256,
// REGION=64, OVERLAP=0 -> 4x4 regions, MAX_M=16.
#define NB 8
#define CIN 32
#define COUT 32
#define SS 256
#define REG 64
#define NMAX 16

// Workspace layout (bytes):
#define AVG_OFF   0
#define NM_OFF    1024
#define USED_OFF  2048
#define C64_OFF   4096
#define CN_OFF    4352
#define Y_OFF     8192
#define XE_OFF    (8u << 20)
#define XO_OFF    (12u << 20)
#define Z_OFF     (16u << 20)

// One block per (r, b): mean of 64x64 region of error signal, fp64 accum.
// Block (0,0) additionally computes the cas tables (one entry per thread).
__global__ void k_avg(const float* __restrict__ err, float* __restrict__ avg,
                      float* __restrict__ cyc64, float* __restrict__ cycN) {
    int r = blockIdx.x, b = blockIdx.y;
    int t = threadIdx.x;
    if (r == 0 && b == 0) {
        if (t < 64) {
            double a = (2.0 * M_PI / 64.0) * (double)t;
            cyc64[t] = (float)(cos(a) + sin(a));
        } else if (t < 64 + 136) {
            int e = t - 64;
            int n = 1;
            while (n * (n + 1) / 2 <= e) ++n;   // smallest n with n(n+1)/2 > e
            int j = e - n * (n - 1) / 2;
            double a = (2.0 * M_PI / (double)n) * (double)j;
            cycN[e] = (float)(cos(a) + sin(a));
        }
    }
    int ri = r >> 2, rj = r & 3;
    const float* base = err + ((size_t)b * SS + ri * REG) * SS + rj * REG;
    double s = 0.0;
    for (int it = 0; it < 16; ++it) {
        int u = it * 4 + (t >> 6);
        int v = t & 63;
        s += (double)base[(size_t)u * SS + v];
    }
    __shared__ double sm[256];
    sm[t] = s;
    __syncthreads();
    for (int w = 128; w > 0; w >>= 1) {
        if (t < w) sm[t] += sm[t + w];
        __syncthreads();
    }
    if (t == 0) avg[r * 8 + b] = (float)(sm[0] / 4096.0);
}

// Single block: per-region batch min/max normalize -> nm, plus used-n flags.
__global__ void k_nm(const float* __restrict__ avg, int* __restrict__ nm,
                     int* __restrict__ used) {
    int t = threadIdx.x;
    if (t < 32) used[t] = 0;
    __syncthreads();
    if (t < 16) {
        int r = t;
        float mn = avg[r * 8], mx = mn;
        for (int b = 1; b < NB; ++b) {
            float v = avg[r * 8 + b];
            mn = fminf(mn, v);
            mx = fmaxf(mx, v);
        }
        float d = mx - mn;
        bool ok = ((double)d > 1e-8);
        for (int b = 0; b < NB; ++b) {
            float norm = ok ? (avg[r * 8 + b] - mn) / d : 0.0f;
            float tt = norm * 15.0f;
            int nv = (int)tt + 1;
            if (nv > NMAX) nv = NMAX;
            nm[b * 16 + r] = nv;
            atomicOr(&used[nv], 1);
        }
    }
}

// One block per (i, r, b): n-corner separable DHT of the 64x64 region, then
// true n x n dht2 via row-column + correction, then Xe/Xo split. 256 threads.
// Stage 1: thread (p1=t>>4, vg=t&15) owns one output float4 — 4 waves of FMA
// in parallel across the 4 SIMDs (the round-5 single-wave version serialized
// this onto one SIMD and regressed 4x on the dominant stage).
__global__ void k_fwd(const float* __restrict__ x, const int* __restrict__ nm,
                      const float* __restrict__ cyc64, const float* __restrict__ cycN,
                      float* __restrict__ Xe, float* __restrict__ Xo) {
    int i = blockIdx.x, r = blockIdx.y, b = blockIdx.z;
    int n = nm[b * 16 + r];
    int nn = n * n;
    int ri = r >> 2, rj = r & 3;
    int t = threadIdx.x;

    __shared__ __align__(16) float R[64 * 64];
    __shared__ __align__(16) float M1[16 * 68];   // stride 68: conflict-free rows
    __shared__ float H[256];
    __shared__ float T1[256];
    __shared__ float T2[256];
    __shared__ float cyc64L[64];
    __shared__ float cnL[16];

    if (t < 64) cyc64L[t] = cyc64[t];
    if (t < n)  cnL[t] = cycN[(n * (n - 1)) / 2 + t];

    const float* base = x + (((size_t)(b * CIN + i)) * SS + ri * REG) * SS + rj * REG;
    float4* R4 = (float4*)R;
    {
        int u0 = t >> 4, c4 = t & 15;
        for (int it = 0; it < 4; ++it) {
            int u = it * 16 + u0;
            R4[u * 16 + c4] = *(const float4*)(base + (size_t)u * SS + c4 * 4);
        }
    }
    __syncthreads();

    // stage 1: M1[p][v] = sum_u cas64(p*u) * R[u][v], p < n. float4 over v.
    {
        int p1 = t >> 4, vg = t & 15;
        if (p1 < n) {
            float4 acc = {0.f, 0.f, 0.f, 0.f};
            int idx = 0;
            for (int u = 0; u < 64; ++u) {
                float c = cyc64L[idx]; idx = (idx + p1) & 63;
                float4 rv = R4[u * 16 + vg];
                acc.x += c * rv.x; acc.y += c * rv.y;
                acc.z += c * rv.z; acc.w += c * rv.w;
            }
            *(float4*)&M1[p1 * 68 + vg * 4] = acc;
        }
    }
    __syncthreads();

    int p = 0, q = 0;
    if (t < nn) { p = t / n; q = t - p * n; }

    // stage 2: H[p][q] = sum_v M1[p][v] * cas64(q*v)
    if (t < nn) {
        float acc = 0.f;
        int idx = 0;
        for (int v = 0; v < 64; ++v) {
            acc += M1[p * 68 + v] * cyc64L[idx];
            idx = (idx + q) & 63;
        }
        H[t] = acc;
    }
    __syncthreads();

    // stage 3: true 2-D DHT of H (n x n) = row-column + correction (2n^3, not n^4)
    if (t < nn) {
        float acc = 0.f;
        int idx = 0;
        for (int v = 0; v < n; ++v) {
            acc += H[p * n + v] * cnL[idx];
            idx += q; if (idx >= n) idx -= n;
        }
        T1[p * n + q] = acc;   // T1[u][q]
    }
    __syncthreads();
    if (t < nn) {
        float acc = 0.f;
        int idx = 0;
        for (int u = 0; u < n; ++u) {
            acc += T1[u * n + q] * cnL[idx];
            idx += p; if (idx >= n) idx -= n;
        }
        T2[t] = acc;           // separable transform
    }
    __syncthreads();
    if (t < nn) {
        int pf = (p == 0) ? 0 : n - p;
        int qf = (q == 0) ? 0 : n - q;
        H[t] = 0.5f * (T2[p * n + q] + T2[pf * n + q] + T2[p * n + qf] - T2[pf * n + qf]);
    }
    __syncthreads();

    if (t < nn) {
        int fk = (t == 0) ? 0 : nn - t;
        float a = H[t], c = H[fk];
        size_t o = (((size_t)(b * 16 + r)) * CIN + i) * 256 + t;
        Xe[o] = 0.5f * (a + c);
        Xo[o] = 0.5f * (a - c);
    }
}

// dht2 of weights[:, :, :n, :n] for each used n, row-column + correction.
__global__ void k_wt(const float* __restrict__ wts, const int* __restrict__ used,
                     const float* __restrict__ cycN, float* __restrict__ Y) {
    int n = blockIdx.y + 1;
    if (!used[n]) return;
    int io = blockIdx.x;
    int t = threadIdx.x;
    int nn = n * n;
    __shared__ float Wt[256];
    __shared__ float T1[256];
    __shared__ float T2[256];
    __shared__ float cnL[16];
    Wt[t] = wts[(size_t)io * 256 + t];
    if (t < n) cnL[t] = cycN[(n * (n - 1)) / 2 + t];
    __syncthreads();
    int p = 0, q = 0;
    if (t < nn) { p = t / n; q = t - p * n; }
    if (t < nn) {
        float acc = 0.f;
        int idx = 0;
        for (int v = 0; v < n; ++v) {
            acc += Wt[p * 16 + v] * cnL[idx];
            idx += q; if (idx >= n) idx -= n;
        }
        T1[p * n + q] = acc;
    }
    __syncthreads();
    if (t < nn) {
        float acc = 0.f;
        int idx = 0;
        for (int u = 0; u < n; ++u) {
            acc += T1[u * n + q] * cnL[idx];
            idx += p; if (idx >= n) idx -= n;
        }
        T2[t] = acc;
    }
    __syncthreads();
    if (t < nn) {
        int pf = (p == 0) ? 0 : n - p;
        int qf = (q == 0) ? 0 : n - q;
        float v = 0.5f * (T2[p * n + q] + T2[pf * n + q] + T2[p * n + qf] - T2[pf * n + qf]);
        int m = n - 1;
        int ps2 = m * (m + 1) * (2 * m + 1) / 6;  // sum of squares 1..m
        Y[(size_t)1024 * ps2 + (size_t)io * nn + t] = v;
    }
}

// Z[o,k] = sum_i Xe[i,k]*Y[io,k] + Xo[i,k]*Y[io,flip(k)].
// grid (8, 128): blockIdx.x = group of 4 outputs, blockIdx.y = (b,r).
__global__ void k_z(const float* __restrict__ Xe, const float* __restrict__ Xo,
                    const float* __restrict__ Y, const int* __restrict__ nm,
                    float* __restrict__ Z) {
    int br = blockIdx.y;
    int og = blockIdx.x * 4;
    int b = br >> 4, r = br & 15;
    int n = nm[b * 16 + r];
    int nn = n * n;
    int t = threadIdx.x;
    if (t >= nn) return;
    int m = n - 1;
    int ps2 = m * (m + 1) * (2 * m + 1) / 6;
    const float* Yb = Y + (size_t)1024 * ps2;
    int fk = (t == 0) ? 0 : nn - t;
    float acc[4] = {0.f, 0.f, 0.f, 0.f};
    size_t xbase = (size_t)br * CIN * 256;
    for (int i = 0; i < CIN; ++i) {
        float xe = Xe[xbase + i * 256 + t];
        float xo = Xo[xbase + i * 256 + t];
        const float* yi = Yb + (size_t)(i * COUT + og) * nn;
#pragma unroll
        for (int oo = 0; oo < 4; ++oo) {
            acc[oo] += xe * yi[oo * nn + t] + xo * yi[oo * nn + fk];
        }
    }
    size_t zbase = (size_t)br * COUT * 256;
#pragma unroll
    for (int oo = 0; oo < 4; ++oo) Z[zbase + (og + oo) * 256 + t] = acc[oo];
}

// One block per (o, r, b): inverse dht2 via row-column + correction (/n^2),
// then n->64 separable expansion (/4096). The final stage register-caches
// each lane's E1 column slice (n float4, unrolled+guarded -> stays in VGPRs)
// and reuses it across the lane's 4 output rows.
__global__ void k_out(const float* __restrict__ Z, const int* __restrict__ nm,
                      const float* __restrict__ cyc64, const float* __restrict__ cycN,
                      float* __restrict__ out) {
    int o = blockIdx.x, r = blockIdx.y, b = blockIdx.z;
    int n = nm[b * 16 + r];
    int nn = n * n;
    int t = threadIdx.x;
    int br = b * 16 + r;

    __shared__ float Zs[256];
    __shared__ float T1[256];
    __shared__ float T2[256];
    __shared__ float Bk[256];
    __shared__ __align__(16) float E1[16 * 64];
    __shared__ float cyc64L[64];
    __shared__ float cnL[16];

    if (t < 64) cyc64L[t] = cyc64[t];
    if (t < n)  cnL[t] = cycN[(n * (n - 1)) / 2 + t];
    if (t < nn) Zs[t] = Z[((size_t)br * COUT + o) * 256 + t];
    __syncthreads();

    int p = 0, q = 0;
    if (t < nn) { p = t / n; q = t - p * n; }

    // inverse dht2 (row-column + correction), / nn
    if (t < nn) {
        float acc = 0.f;
        int idx = 0;
        for (int v = 0; v < n; ++v) {
            acc += Zs[p * n + v] * cnL[idx];
            idx += q; if (idx >= n) idx -= n;
        }
        T1[p * n + q] = acc;
    }
    __syncthreads();
    if (t < nn) {
        float acc = 0.f;
        int idx = 0;
        for (int u = 0; u < n; ++u) {
            acc += T1[u * n + q] * cnL[idx];
            idx += p; if (idx >= n) idx -= n;
        }
        T2[t] = acc;
    }
    __syncthreads();
    if (t < nn) {
        int pf = (p == 0) ? 0 : n - p;
        int qf = (q == 0) ? 0 : n - q;
        Bk[t] = 0.5f * (T2[p * n + q] + T2[pf * n + q] + T2[p * n + qf] - T2[pf * n + qf])
                / (float)nn;
    }
    __syncthreads();

    // E1[p][v] = sum_q Bk[p*n+q] * cas64(q*v)
    for (int mm = t; mm < n * 64; mm += 256) {
        int pp = mm >> 6, v = mm & 63;
        float acc = 0.f;
        int idx = 0;
        for (int qq = 0; qq < n; ++qq) {
            acc += Bk[pp * n + qq] * cyc64L[idx];
            idx = (idx + v) & 63;
        }
        E1[pp * 64 + v] = acc;
    }
    __syncthreads();

    // out[u][v] = (1/4096) sum_p E1[p][v] * cas64(p*u); E1 slice in registers.
    int ri = r >> 2, rj = r & 3;
    float* ob = out + (((size_t)(b * COUT + o)) * SS + ri * REG) * SS + rj * REG;
    const float4* E14 = (const float4*)E1;
    const float inv = 1.0f / 4096.0f;
    int u0 = t >> 4, vg = t & 15;
    float4 e[16];
#pragma unroll
    for (int pp = 0; pp < 16; ++pp) {
        if (pp < n) e[pp] = E14[pp * 16 + vg];
    }
    for (int it = 0; it < 4; ++it) {
        int u = it * 16 + u0;
        float4 acc = {0.f, 0.f, 0.f, 0.f};
#pragma unroll
        for (int pp = 0; pp < 16; ++pp) {
            if (pp < n) {
                float c = cyc64L[(pp * u) & 63];
                acc.x += c * e[pp].x; acc.y += c * e[pp].y;
                acc.z += c * e[pp].z; acc.w += c * e[pp].w;
            }
        }
        acc.x *= inv; acc.y *= inv; acc.z *= inv; acc.w *= inv;
        *(float4*)(ob + (size_t)u * SS + vg * 4) = acc;
    }
}

extern "C" void kernel_launch(void* const* d_in, const int* in_sizes, int n_in,
                              void* d_out, int out_size, void* d_ws, size_t ws_size,
                              hipStream_t stream) {
    const float* x   = (const float*)d_in[0];
    const float* err = (const float*)d_in[1];
    const float* wts = (const float*)d_in[2];
    float* out = (float*)d_out;
    char* ws = (char*)d_ws;

    float* avg   = (float*)(ws + AVG_OFF);
    int*   nm    = (int*)  (ws + NM_OFF);
    int*   used  = (int*)  (ws + USED_OFF);
    float* cyc64 = (float*)(ws + C64_OFF);
    float* cycN  = (float*)(ws + CN_OFF);
    float* Y     = (float*)(ws + Y_OFF);
    float* Xe    = (float*)(ws + XE_OFF);
    float* Xo    = (float*)(ws + XO_OFF);
    float* Z     = (float*)(ws + Z_OFF);

    k_avg<<<dim3(16, NB), 256, 0, stream>>>(err, avg, cyc64, cycN);
    k_nm<<<1, 32, 0, stream>>>(avg, nm, used);
    k_fwd<<<dim3(CIN, 16, NB), 256, 0, stream>>>(x, nm, cyc64, cycN, Xe, Xo);
    k_wt<<<dim3(CIN * COUT, NMAX), 256, 0, stream>>>(wts, used, cycN, Y);
    k_z<<<dim3(8, 128), 256, 0, stream>>>(Xe, Xo, Y, nm, Z);
    k_out<<<dim3(COUT, 16, NB), 256, 0, stream>>>(Z, nm, cyc64, cycN, out);
}